// Round 1
// 1353.109 us; speedup vs baseline: 1.9945x; 1.9945x over previous
//
#include <hip/hip_runtime.h>

// WindowAttention: B_=4096, N=49, C=384, H=12, hd=32, nW=1024
// Stage 1 (attn_kernel): per-window fused qkv GEMM + attention, writes
//   per-token bf16 attn-output (384 ch) into the FIRST 768 bytes of each
//   token's 1536-byte slot in d_out.
// Stage 2 (proj_kernel): in-place proj GEMM over d_out (stages its token
//   rows to LDS before overwriting).
//
// R1 change: weights are pre-packed (conv_w_kernel) into wave-coalesced MFMA
// fragment order and loaded straight from global/L2 inside the MFMA loops.
// This deletes Ws[96][392] (75 KiB) from attn (LDS 148->74.4 KiB => 2
// blocks/CU instead of 1) and Wlds from proj (LDS 100->49 KiB => 3
// blocks/CU, barrier-free main loop). Weights total 884 KB bf16 -> L2-hot.

#define SCALE_Q 0.17677669529663687f

typedef __bf16 bf16x8 __attribute__((ext_vector_type(8)));
typedef float f32x4 __attribute__((ext_vector_type(4)));

__device__ __forceinline__ unsigned short f2bf(float f) {
  union { float f; unsigned int u; } c; c.f = f;
  unsigned int u = c.u;
  return (unsigned short)((u + 0x7FFFu + ((u >> 16) & 1u)) >> 16);
}

__device__ __forceinline__ f32x4 mfma16(bf16x8 a, bf16x8 b, f32x4 c) {
  return __builtin_amdgcn_mfma_f32_16x16x32_bf16(a, b, c, 0, 0, 0);
}

// fallback path: build a bf16x8 B-fragment from 8 consecutive f32
__device__ __forceinline__ bf16x8 cvt8_frag(const float* __restrict__ src) {
  const float4 a = *(const float4*)src;
  const float4 b = *(const float4*)(src + 4);
  union { bf16x8 v; unsigned short u[8]; } c;
  c.u[0] = f2bf(a.x); c.u[1] = f2bf(a.y); c.u[2] = f2bf(a.z); c.u[3] = f2bf(a.w);
  c.u[4] = f2bf(b.x); c.u[5] = f2bf(b.y); c.u[6] = f2bf(b.z); c.u[7] = f2bf(b.w);
  return c.v;
}

// Pack fp32 weights -> bf16 in MFMA-fragment order (one contiguous 1 KiB
// line per (tile, k-chunk) = 64 lanes x 16 B), so the GEMM B-operand loads
// are single fully-coalesced global_load_dwordx4 per lane.
//
// qkv frags f in [0, 55296):  lane=f&63, kk=(f>>6)%12, t=((f>>6)/12)%6,
//   h=(f>>6)/72.  n96=t*16+(lane&15); src row=(n96>>5)*384+h*32+(n96&31);
//   src col=kk*32+(lane>>4)*8.
// proj frags p in [0, 18432): lane=p&63, kk=(p>>6)%12, t=(p>>6)/12.
//   src row=t*16+(lane&15); src col=kk*32+(lane>>4)*8.
__global__ void conv_w_kernel(const float* __restrict__ qkv_w,
                              const float* __restrict__ proj_w,
                              unsigned short* __restrict__ wbf) {
  const int f = blockIdx.x * 256 + threadIdx.x;
  const int lane = f & 63;
  const int l15 = lane & 15;
  const int quad = (lane >> 4) & 3;
  const float* src;
  unsigned short* dst;
  if (f < 55296) {
    const int rest = f >> 6;
    const int kk = rest % 12;
    const int ht = rest / 12;
    const int t = ht % 6, h = ht / 6;
    const int n96 = t * 16 + l15;
    const int grow = (n96 >> 5) * 384 + h * 32 + (n96 & 31);
    src = qkv_w + (size_t)grow * 384 + kk * 32 + quad * 8;
    dst = wbf + (size_t)f * 8;
  } else if (f < 73728) {
    const int p = f - 55296;
    const int rest = p >> 6;
    const int kk = rest % 12, t = rest / 12;
    src = proj_w + (size_t)(t * 16 + l15) * 384 + kk * 32 + quad * 8;
    dst = wbf + 442368 + (size_t)p * 8;
  } else {
    return;
  }
  const float4 a = *(const float4*)src;
  const float4 b = *(const float4*)(src + 4);
  ushort4 s0, s1;
  s0.x = f2bf(a.x); s0.y = f2bf(a.y); s0.z = f2bf(a.z); s0.w = f2bf(a.w);
  s1.x = f2bf(b.x); s1.y = f2bf(b.y); s1.z = f2bf(b.z); s1.w = f2bf(b.w);
  *(ushort4*)dst = s0;
  *(ushort4*)(dst + 4) = s1;
}

template <bool PRECONV>
__global__ __launch_bounds__(256, 2)
void attn_kernel(const float* __restrict__ x, const float* __restrict__ mask,
                 const float* __restrict__ qkv_w, const float* __restrict__ qkv_b,
                 const float* __restrict__ rpb, const float* __restrict__ lamb,
                 const unsigned short* __restrict__ qkv_w_bf,
                 float* __restrict__ out) {
  // M-tiles {0,16,32,33}: overlapped tiles cover rows 0..48 with no padding.
  // Strides padded so wave64 b128 frag reads are <=2-way bank aliased (free).
  // LDS total ~74.4 KiB -> 2 blocks/CU.
  __shared__ __align__(16) unsigned short Xs[49][392];   // x window, bf16
  __shared__ __align__(16) unsigned short Qs[49][40];    // q*scale (also O buf)
  __shared__ __align__(16) unsigned short Ks[49][40];    // k
  __shared__ __align__(16) unsigned short Vt[32][72];    // v transposed [d][j]
  __shared__ __align__(16) float          Ss[49][52];    // scores fp32
  __shared__ __align__(16) unsigned short Pb[49][72];    // softmaxed P, bf16
  __shared__ float Rpb[169 * 12];

  const int tid  = threadIdx.x;
  const int b    = blockIdx.x;
  const int lane = tid & 63;
  const int wv   = tid >> 6;        // 0..3
  const int l15  = lane & 15;
  const int quad = lane >> 4;       // 0..3

  // ---- stage x window (fp32 -> bf16), rpb table, zero Vt pad cols ----
  {
    const float* xw = x + (size_t)b * (49 * 384);
    for (int t = tid; t < 49 * 96; t += 256) {
      int row = t / 96, c4 = t - row * 96;
      const float4 v = *(const float4*)(xw + row * 384 + c4 * 4);
      ushort4 s;
      s.x = f2bf(v.x); s.y = f2bf(v.y); s.z = f2bf(v.z); s.w = f2bf(v.w);
      *(ushort4*)&Xs[row][c4 * 4] = s;
    }
    for (int t = tid; t < 169 * 12; t += 256) Rpb[t] = rpb[t];
    for (int t = tid; t < 32 * 23; t += 256) {       // Vt[:,49..71] = 0
      int d = t / 23, j = 49 + (t - d * 23);
      Vt[d][j] = 0;
    }
  }
  __syncthreads();

  const float* mbase = mask + (size_t)(b & 1023) * (49 * 49);

  for (int h = 0; h < 12; ++h) {
    // ---- qkv GEMM: M=49 (tiles 0,16,32,33), N=96, K=384.
    //      B-fragments streamed from global (packed, L2-hot). ----
    {
      const int mp = wv >> 1, g = wv & 1;
      const int m0a = mp * 32;            // 0 or 32
      const int m0b = mp ? 33 : 16;       // 16 or 33
      const unsigned short* wg =
          qkv_w_bf + ((size_t)(h * 6 + g * 3) * 12) * 512 + lane * 8;
      f32x4 acc[2][3] = {};
      for (int kk = 0; kk < 12; ++kk) {
        const int k0 = kk * 32 + quad * 8;
        const bf16x8 a0 = *(const bf16x8*)&Xs[m0a + l15][k0];
        const bf16x8 a1 = *(const bf16x8*)&Xs[m0b + l15][k0];
#pragma unroll
        for (int e = 0; e < 3; ++e) {
          bf16x8 bb;
          if (PRECONV) {
            bb = *(const bf16x8*)(wg + (e * 12 + kk) * 512);
          } else {
            const int n96 = (g * 3 + e) * 16 + l15;
            const int grow = (n96 >> 5) * 384 + h * 32 + (n96 & 31);
            bb = cvt8_frag(qkv_w + (size_t)grow * 384 + k0);
          }
          acc[0][e] = mfma16(a0, bb, acc[0][e]);
          acc[1][e] = mfma16(a1, bb, acc[1][e]);
        }
      }
#pragma unroll
      for (int im = 0; im < 2; ++im) {
        const int m0 = im ? m0b : m0a;
#pragma unroll
        for (int e = 0; e < 3; ++e) {
          const int n96 = (g * 3 + e) * 16 + l15;
          const int sub = n96 >> 5, c32 = n96 & 31;
          const float bias = qkv_b[sub * 384 + h * 32 + c32];
#pragma unroll
          for (int r = 0; r < 4; ++r) {
            const int row = m0 + quad * 4 + r;   // <= 48 always
            const float val = acc[im][e][r] + bias;
            if (sub == 0)      Qs[row][c32] = f2bf(val * SCALE_Q);
            else if (sub == 1) Ks[row][c32] = f2bf(val);
            else               Vt[c32][row] = f2bf(val);
          }
        }
      }
    }
    __syncthreads();

    // ---- S = q k^T : K=32 (single mfma per 16x16 tile) ----
    {
      const int m0 = (wv * 16 > 33) ? 33 : wv * 16;
      const bf16x8 aq = *(const bf16x8*)&Qs[m0 + l15][quad * 8];
      f32x4 sacc[4] = {};
#pragma unroll
      for (int nt = 0; nt < 4; ++nt) {
        const int n0 = (nt * 16 > 33) ? 33 : nt * 16;
        const bf16x8 bk = *(const bf16x8*)&Ks[n0 + l15][quad * 8];
        sacc[nt] = mfma16(aq, bk, sacc[nt]);
      }
#pragma unroll
      for (int nt = 0; nt < 4; ++nt) {
        const int n0 = (nt * 16 > 33) ? 33 : nt * 16;
#pragma unroll
        for (int r = 0; r < 4; ++r)
          Ss[m0 + quad * 4 + r][n0 + l15] = sacc[nt][r];
      }
    }
    __syncthreads();

    // ---- softmax (+rel-pos bias, +mask, +lamb rescale), 4 lanes/row ----
    if (tid < 196) {
      const int i = tid >> 2, l4 = tid & 3;
      const int ri = (i * 37) >> 8;       // i/7 for i<49
      const int ci = i - ri * 7;
      const float* mrow = mbase + i * 49;
      float sv[13];
      float mx = -1e30f;
#pragma unroll
      for (int jj = 0; jj < 13; ++jj) {
        const int j = l4 + jj * 4;
        float val = -1e30f;
        if (j < 49) {
          const int rj = (j * 37) >> 8;
          const int cj = j - rj * 7;
          const int rel = (ri - rj + 6) * 13 + (ci - cj + 6);
          val = Ss[i][j] + Rpb[rel * 12 + h] + mrow[j];
        }
        sv[jj] = val;
        mx = fmaxf(mx, val);
      }
      mx = fmaxf(mx, __shfl_xor(mx, 1));
      mx = fmaxf(mx, __shfl_xor(mx, 2));
      float sum = 0.f;
#pragma unroll
      for (int jj = 0; jj < 13; ++jj) {
        const int j = l4 + jj * 4;
        const float e = (j < 49) ? __expf(sv[jj] - mx) : 0.f;
        sv[jj] = e;
        sum += e;
      }
      sum += __shfl_xor(sum, 1);
      sum += __shfl_xor(sum, 2);
      const float inv = 1.f / sum;
      const float lam = lamb[h];
      const float sc = 1.f + lam;
      const float ad = -lam * (1.0f / 49.0f);
#pragma unroll
      for (int jj = 0; jj < 16; ++jj) {
        const int j = l4 + jj * 4;          // covers 0..63
        float p = 0.f;
        if (j < 49) p = sv[jj] * inv * sc + ad;
        Pb[i][j] = f2bf(p);
      }
    }
    __syncthreads();

    // ---- O = P V : M=49 tiles, N=32, K=64 (cols 49..63 of Pb are zero) ----
    {
      const int m0 = (wv * 16 > 33) ? 33 : wv * 16;
      f32x4 oacc[2] = {};
#pragma unroll
      for (int kk = 0; kk < 2; ++kk) {
        const int k0 = kk * 32 + quad * 8;
        const bf16x8 ap = *(const bf16x8*)&Pb[m0 + l15][k0];
#pragma unroll
        for (int nt = 0; nt < 2; ++nt) {
          const bf16x8 bv = *(const bf16x8*)&Vt[nt * 16 + l15][k0];
          oacc[nt] = mfma16(ap, bv, oacc[nt]);
        }
      }
#pragma unroll
      for (int nt = 0; nt < 2; ++nt)
#pragma unroll
        for (int r = 0; r < 4; ++r)
          Qs[m0 + quad * 4 + r][nt * 16 + l15] = f2bf(oacc[nt][r]);  // O buf
    }
    __syncthreads();

    // ---- coalesced bf16 write-out into d_out row slots ----
    if (tid < 196) {
      const int row = tid >> 2, ch = tid & 3;
      const uint4 v = *(const uint4*)&Qs[row][ch * 8];
      *(uint4*)((char*)out + (size_t)(b * 49 + row) * 1536 + h * 64 + ch * 16) = v;
    }
    __syncthreads();
  }
}

template <bool PRECONV>
__global__ __launch_bounds__(256, 3)
void proj_kernel(const float* __restrict__ proj_w, const float* __restrict__ proj_b,
                 const unsigned short* __restrict__ proj_w_bf,
                 float* __restrict__ out) {
  // LDS = Ains only (49 KiB) -> 3 blocks/CU; main loop is barrier-free.
  __shared__ __align__(16) unsigned short Ains[64][392];
  const int tid  = threadIdx.x;
  const int mb   = blockIdx.x;           // 3136 blocks x 64 tokens
  const int lane = tid & 63;
  const int wv   = tid >> 6;
  const int l15  = lane & 15;
  const int quad = lane >> 4;

  // stage this block's 64 token rows (bf16, first 768B of each slot)
  for (int t = tid; t < 64 * 48; t += 256) {
    int row = t / 48, ch = t - row * 48;
    const uint4 v = *(const uint4*)((const char*)out +
        (size_t)(mb * 64 + row) * 1536 + ch * 16);
    *(uint4*)&Ains[row][ch * 8] = v;
  }
  __syncthreads();   // after this, in-place overwrite of our slots is safe

  const int mp = wv >> 1, np = wv & 1;
  const unsigned short* pw = proj_w_bf + lane * 8;

  for (int nc = 0; nc < 6; ++nc) {
    const int t0 = nc * 4 + np * 2;      // packed n-tile index (t0, t0+1)
    f32x4 acc[2][2] = {};
    for (int kk = 0; kk < 12; ++kk) {
      const int k0 = kk * 32 + quad * 8;
      const bf16x8 a0 = *(const bf16x8*)&Ains[mp * 32 + l15][k0];
      const bf16x8 a1 = *(const bf16x8*)&Ains[mp * 32 + 16 + l15][k0];
      bf16x8 b0, b1;
      if (PRECONV) {
        b0 = *(const bf16x8*)(pw + (t0 * 12 + kk) * 512);
        b1 = *(const bf16x8*)(pw + ((t0 + 1) * 12 + kk) * 512);
      } else {
        b0 = cvt8_frag(proj_w + (size_t)(t0 * 16 + l15) * 384 + k0);
        b1 = cvt8_frag(proj_w + (size_t)((t0 + 1) * 16 + l15) * 384 + k0);
      }
      acc[0][0] = mfma16(a0, b0, acc[0][0]);
      acc[0][1] = mfma16(a0, b1, acc[0][1]);
      acc[1][0] = mfma16(a1, b0, acc[1][0]);
      acc[1][1] = mfma16(a1, b1, acc[1][1]);
    }
#pragma unroll
    for (int im = 0; im < 2; ++im) {
#pragma unroll
      for (int jn = 0; jn < 2; ++jn) {
        const int col = nc * 64 + np * 32 + jn * 16 + l15;
        const float pb = proj_b[col];
#pragma unroll
        for (int r = 0; r < 4; ++r) {
          const int token = mb * 64 + mp * 32 + im * 16 + quad * 4 + r;
          out[(size_t)token * 384 + col] = acc[im][jn][r] + pb;
        }
      }
    }
  }
}

extern "C" void kernel_launch(void* const* d_in, const int* in_sizes, int n_in,
                              void* d_out, int out_size, void* d_ws, size_t ws_size,
                              hipStream_t stream) {
  const float* x      = (const float*)d_in[0];
  const float* mask   = (const float*)d_in[1];
  const float* qkv_w  = (const float*)d_in[2];
  const float* qkv_b  = (const float*)d_in[3];
  const float* proj_w = (const float*)d_in[4];
  const float* proj_b = (const float*)d_in[5];
  const float* rpb    = (const float*)d_in[6];
  const float* lamb   = (const float*)d_in[7];
  float* out = (float*)d_out;

  const size_t conv_bytes = (size_t)(442368 + 147456) * sizeof(unsigned short);
  unsigned short* wbf = (unsigned short*)d_ws;

  if (ws_size >= conv_bytes) {
    conv_w_kernel<<<288, 256, 0, stream>>>(qkv_w, proj_w, wbf);
    attn_kernel<true><<<4096, 256, 0, stream>>>(x, mask, qkv_w, qkv_b, rpb, lamb,
                                                wbf, out);
    proj_kernel<true><<<3136, 256, 0, stream>>>(proj_w, proj_b, wbf + 442368, out);
  } else {
    attn_kernel<false><<<4096, 256, 0, stream>>>(x, mask, qkv_w, qkv_b, rpb, lamb,
                                                 nullptr, out);
    proj_kernel<false><<<3136, 256, 0, stream>>>(proj_w, proj_b, nullptr, out);
  }
}